// Round 1
// baseline (69.289 us; speedup 1.0000x reference)
//
#include <hip/hip_runtime.h>

typedef float f4 __attribute__((ext_vector_type(4)));

#define LL 64
#define BB 2048
#define DD 512

__device__ __forceinline__ float fexp2(float x){ return __builtin_amdgcn_exp2f(x); }
__device__ __forceinline__ float frcpf_(float x){ return __builtin_amdgcn_rcpf(x); }
// sigmoid(z) = 1/(1+2^(-z*log2e))
__device__ __forceinline__ float fsigm(float z){ return frcpf_(1.0f + fexp2(-1.442695040888963f*z)); }
// tanh(z) = 1 - 2/(1+2^(z*2*log2e))
__device__ __forceinline__ float ftanh_(float z){ return 1.0f - 2.0f*frcpf_(1.0f + fexp2(2.885390081777927f*z)); }

__device__ __forceinline__ f4 ld4(const float* __restrict__ p){
  return *(const f4*)p;
}

__global__ __launch_bounds__(128, 3) void rnn_fused_kernel(
    const float* __restrict__ x,
    const float* __restrict__ wxp, const float* __restrict__ wgp,
    const float* __restrict__ whp, const float* __restrict__ wup,
    const float* __restrict__ mp,  const float* __restrict__ fcw,
    const float* __restrict__ fcb, float* __restrict__ out)
{
  __shared__ float part[LL][33];   // [l][quad-group], +1 pad -> conflict-free
  const int tid = threadIdx.x;
  const int b   = blockIdx.x;
  const int d0  = tid << 2;        // 4 d's per thread, 128 threads cover D=512
  const int grp = tid >> 2;        // 32 quad-groups per block

  const f4 fw = ld4(fcw + d0);
  const float* xb_base = x + (size_t)b * DD + d0;

  // ---- t = 0: x_bar[0] = x[0]; h0 = tanh(x0*wx0); x_bar[1] = h0*wg0 + x0
  f4 x0  = ld4(xb_base);
  f4 w0x = ld4(wxp + d0);
  f4 w0g = ld4(wgp + d0);

  float c0 = x0[0]*fw[0] + x0[1]*fw[1] + x0[2]*fw[2] + x0[3]*fw[3];
  c0 += __shfl_xor(c0, 1);
  c0 += __shfl_xor(c0, 2);
  if ((tid & 3) == 0) part[0][grp] = c0;

  f4 h0v, h, xb;
  float c1 = 0.0f;
  #pragma unroll
  for (int j = 0; j < 4; ++j){
    h0v[j] = ftanh_(x0[j] * w0x[j]);
    xb[j]  = h0v[j] * w0g[j] + x0[j];
    c1    += xb[j] * fw[j];
  }
  h = h0v;
  c1 += __shfl_xor(c1, 1);
  c1 += __shfl_xor(c1, 2);
  if ((tid & 3) == 0) part[1][grp] = c1;

  // ---- prefetch t=1 (distance-1 software pipeline)
  f4 xt = ld4(xb_base + (size_t)BB * DD);
  f4 wx = ld4(wxp + DD + d0);
  f4 wg = ld4(wgp + DD + d0);
  f4 wh = ld4(whp + DD + d0);
  f4 wu = ld4(wup + DD + d0);
  f4 mm = ld4(mp  + DD + d0);

  // ---- main scan: t = 1..62 (x[63]/w[63] are never used by the reference)
  #pragma unroll 1
  for (int t = 1; t < LL - 1; ++t){
    const int tn = (t < LL - 2) ? (t + 1) : (LL - 2);  // clamped prefetch
    f4 xn  = ld4(xb_base + (size_t)tn * BB * DD);
    f4 wxn = ld4(wxp + tn * DD + d0);
    f4 wgn = ld4(wgp + tn * DD + d0);
    f4 whn = ld4(whp + tn * DD + d0);
    f4 wun = ld4(wup + tn * DD + d0);
    f4 mmn = ld4(mp  + tn * DD + d0);

    float cc = 0.0f;
    #pragma unroll
    for (int j = 0; j < 4; ++j){
      float xtr  = xb[j] + mm[j] * (xt[j] - xb[j]);    // x*m + xb*(1-m)
      float u    = ftanh_(xtr * wx[j]);
      float fpre = h[j] * wh[j] + u * wu[j];
      float f    = fsigm(fpre) * mm[j];
      float hn   = f * h[j] + fminf(1.0f - f, u);
      hn         = fmaxf(hn, h0v[j]);                  // h0 + relu(h-h0)
      h[j]  = hn;
      float nb = hn * wg[j] + xtr;                     // x_bar carry
      xb[j] = nb;
      cc += nb * fw[j];
    }
    cc += __shfl_xor(cc, 1);
    cc += __shfl_xor(cc, 2);
    if ((tid & 3) == 0) part[t + 1][grp] = cc;

    xt = xn; wx = wxn; wg = wgn; wh = whn; wu = wun; mm = mmn;
  }

  __syncthreads();

  // ---- epilogue: reduce 32 quad-partials per l, sigmoid, store
  if (tid < LL){
    float s = 0.0f;
    #pragma unroll
    for (int j = 0; j < 32; ++j) s += part[tid][j];
    out[(size_t)tid * BB + b] = fsigm(s + fcb[0]);
  }
}

extern "C" void kernel_launch(void* const* d_in, const int* in_sizes, int n_in,
                              void* d_out, int out_size, void* d_ws, size_t ws_size,
                              hipStream_t stream)
{
  const float* x   = (const float*)d_in[0];
  const float* wx  = (const float*)d_in[1];
  const float* wg  = (const float*)d_in[2];
  const float* wh  = (const float*)d_in[3];
  const float* wu  = (const float*)d_in[4];
  const float* m   = (const float*)d_in[5];
  const float* fcw = (const float*)d_in[6];
  const float* fcb = (const float*)d_in[7];
  float* out = (float*)d_out;
  rnn_fused_kernel<<<dim3(BB), dim3(128), 0, stream>>>(x, wx, wg, wh, wu, m, fcw, fcb, out);
}